// Round 1
// baseline (331.708 us; speedup 1.0000x reference)
//
#include <hip/hip_runtime.h>

typedef __attribute__((ext_vector_type(8))) short bf16x8;
typedef __attribute__((ext_vector_type(4))) float f32x4;

#define D_MODEL 1024
#define NHEADS 16
#define HDIM 64
#define SEQ 2048
#define BATCH 2
#define MROWS (BATCH*SEQ)   // 4096
#define NQKV (3*D_MODEL)    // 3072

__device__ __forceinline__ unsigned short f2bf(float f) {
  unsigned int u = __float_as_uint(f);
  u += 0x7FFF + ((u >> 16) & 1);   // RNE
  return (unsigned short)(u >> 16);
}

__global__ void cvt_bf16_kernel(const float4* __restrict__ src,
                                ushort4* __restrict__ dst, int n4) {
  int i = blockIdx.x * blockDim.x + threadIdx.x;
  if (i < n4) {
    float4 v = src[i];
    ushort4 o;
    o.x = f2bf(v.x); o.y = f2bf(v.y); o.z = f2bf(v.z); o.w = f2bf(v.w);
    dst[i] = o;
  }
}

// C[M,N] = A[M,K](bf16) @ B[N,K]^T(bf16) + bias
// MODE 0: scatter epilogue into Q/K/V^T bf16 (QKV projection)
// MODE 1: plain fp32 store (output projection)
template<int MODE>
__global__ __launch_bounds__(256) void gemm_bt_kernel(
    const unsigned short* __restrict__ A,
    const unsigned short* __restrict__ Bm,
    const float* __restrict__ bias,
    float* __restrict__ outF,
    unsigned short* __restrict__ Qb,
    unsigned short* __restrict__ Kb,
    unsigned short* __restrict__ VTb,
    int M, int N, int K)
{
  __shared__ __align__(16) unsigned short As[128*32];
  __shared__ __align__(16) unsigned short Bs[128*32];
  const int tid = threadIdx.x;
  const int wave = tid >> 6, lane = tid & 63;
  const int lm = lane & 15, quad = lane >> 4;
  const int wm = (wave >> 1) * 64, wn = (wave & 1) * 64;
  const int m0 = blockIdx.y * 128, n0 = blockIdx.x * 128;

  f32x4 acc[4][4] = {};

  for (int k0 = 0; k0 < K; k0 += 32) {
    __syncthreads();
#pragma unroll
    for (int i = 0; i < 2; i++) {
      int linear = (i * 256 + tid) * 8;
      int row = linear >> 5, col = linear & 31;
      *(uint4*)&As[linear] = *(const uint4*)&A[(size_t)(m0 + row) * K + k0 + col];
      *(uint4*)&Bs[linear] = *(const uint4*)&Bm[(size_t)(n0 + row) * K + k0 + col];
    }
    __syncthreads();
    bf16x8 af[4], bfr[4];
#pragma unroll
    for (int mi = 0; mi < 4; mi++)
      af[mi] = *(const bf16x8*)&As[(wm + mi*16 + lm)*32 + quad*8];
#pragma unroll
    for (int ni = 0; ni < 4; ni++)
      bfr[ni] = *(const bf16x8*)&Bs[(wn + ni*16 + lm)*32 + quad*8];
#pragma unroll
    for (int mi = 0; mi < 4; mi++)
#pragma unroll
      for (int ni = 0; ni < 4; ni++)
        acc[mi][ni] = __builtin_amdgcn_mfma_f32_16x16x32_bf16(af[mi], bfr[ni], acc[mi][ni], 0, 0, 0);
  }

#pragma unroll
  for (int mi = 0; mi < 4; mi++)
#pragma unroll
    for (int ni = 0; ni < 4; ni++)
#pragma unroll
      for (int r = 0; r < 4; r++) {
        int row = m0 + wm + mi*16 + quad*4 + r;   // C/D: row=(lane>>4)*4+reg
        int col = n0 + wn + ni*16 + lm;           //      col=lane&15
        float v = acc[mi][ni][r] + bias[col];
        if (MODE == 1) {
          outF[(size_t)row * N + col] = v;
        } else {
          int b = row >> 11, s = row & (SEQ - 1);
          int h = col / 192;
          int rr = col - h * 192;
          int t = rr >> 6, e = rr & 63;
          int bh = b * NHEADS + h;
          if (t == 0)      Qb[((size_t)bh*SEQ + s)*HDIM + e] = f2bf(v * 0.125f);
          else if (t == 1) Kb[((size_t)bh*SEQ + s)*HDIM + e] = f2bf(v);
          else             VTb[((size_t)bh*HDIM + e)*SEQ + s] = f2bf(v);
        }
      }
}

// Causal flash attention. Grid (S/128, B*H). 4 waves; wave w owns Q rows
// [q0+w*32, q0+w*32+32). 32-key tiles staged in LDS, online softmax.
__global__ __launch_bounds__(256) void flash_attn_kernel(
    const unsigned short* __restrict__ Qb,
    const unsigned short* __restrict__ Kb,
    const unsigned short* __restrict__ VTb,
    unsigned short* __restrict__ Ob)
{
  const int qt = blockIdx.x;
  const int bh = blockIdx.y;
  const int tid = threadIdx.x;
  const int wave = tid >> 6, lane = tid & 63;
  const int lm = lane & 15, quad = lane >> 4;
  const int q0 = qt * 128;
  const int rowbase = q0 + wave * 32;

  __shared__ __align__(16) unsigned short Ks[32*64];   // [key][e]
  __shared__ __align__(16) unsigned short Vs[64*32];   // [e][key]  (V^T)
  __shared__ __align__(16) unsigned short Ps[4][32*32]; // per-wave P [row][key]

  // Q fragments (A-operand: A[m=lane&15][k=quad*8+j]), Q pre-scaled by 1/8
  bf16x8 qf[2][2];
#pragma unroll
  for (int mi = 0; mi < 2; mi++)
#pragma unroll
    for (int kc = 0; kc < 2; kc++)
      qf[mi][kc] = *(const bf16x8*)&Qb[((size_t)bh*SEQ + rowbase + mi*16 + lm)*HDIM + kc*32 + quad*8];

  f32x4 o[2][4] = {};
  float mst[2][4], lst[2][4];
#pragma unroll
  for (int mi = 0; mi < 2; mi++)
#pragma unroll
    for (int r = 0; r < 4; r++) { mst[mi][r] = -1e30f; lst[mi][r] = 0.f; }

  const int nkt = (q0 + 128) >> 5;
  for (int kt = 0; kt < nkt; ++kt) {
    const int k0 = kt << 5;
    __syncthreads();
    {
      int linear = tid * 8;
      int key = linear >> 6, e = linear & 63;
      *(uint4*)&Ks[linear] = *(const uint4*)&Kb[((size_t)bh*SEQ + k0 + key)*HDIM + e];
      int e2 = linear >> 5, ky = linear & 31;
      *(uint4*)&Vs[linear] = *(const uint4*)&VTb[((size_t)bh*HDIM + e2)*SEQ + k0 + ky];
    }
    __syncthreads();

    // S = Q @ K^T  (already scaled): 2 m-tiles x 2 n-tiles x 2 k-chunks
    f32x4 sc[2][2] = {};
#pragma unroll
    for (int kc = 0; kc < 2; kc++) {
      bf16x8 kf[2];
#pragma unroll
      for (int ni = 0; ni < 2; ni++)
        kf[ni] = *(const bf16x8*)&Ks[(ni*16 + lm)*HDIM + kc*32 + quad*8];
#pragma unroll
      for (int mi = 0; mi < 2; mi++)
#pragma unroll
        for (int ni = 0; ni < 2; ni++)
          sc[mi][ni] = __builtin_amdgcn_mfma_f32_16x16x32_bf16(qf[mi][kc], kf[ni], sc[mi][ni], 0, 0, 0);
    }

    const bool diag = (k0 + 31 > rowbase);
#pragma unroll
    for (int mi = 0; mi < 2; mi++) {
#pragma unroll
      for (int r = 0; r < 4; r++) {
        int grow = rowbase + mi*16 + quad*4 + r;
        float s0 = sc[mi][0][r], s1 = sc[mi][1][r];
        if (diag) {
          if (k0 + lm > grow)      s0 = -1e30f;
          if (k0 + 16 + lm > grow) s1 = -1e30f;
        }
        float mx = fmaxf(s0, s1);
#pragma unroll
        for (int off = 1; off < 16; off <<= 1)
          mx = fmaxf(mx, __shfl_xor(mx, off, 64));
        float mnew = fmaxf(mst[mi][r], mx);
        float alpha = __expf(mst[mi][r] - mnew);
        float p0 = __expf(s0 - mnew);
        float p1 = __expf(s1 - mnew);
        float ps = p0 + p1;
#pragma unroll
        for (int off = 1; off < 16; off <<= 1)
          ps += __shfl_xor(ps, off, 64);
        lst[mi][r] = lst[mi][r] * alpha + ps;
        mst[mi][r] = mnew;
#pragma unroll
        for (int ni = 0; ni < 4; ni++) o[mi][ni][r] *= alpha;
        int prow = mi*16 + quad*4 + r;
        Ps[wave][prow*32 + lm]      = f2bf(p0);
        Ps[wave][prow*32 + 16 + lm] = f2bf(p1);
      }
    }
    // drain same-wave cross-lane LDS writes before A-fragment reads
    asm volatile("s_waitcnt lgkmcnt(0)" ::: "memory");

    // O += P @ V : A from Ps (per-wave), B from Vs (V^T rows contiguous in key)
    bf16x8 vf[4];
#pragma unroll
    for (int ni = 0; ni < 4; ni++)
      vf[ni] = *(const bf16x8*)&Vs[(ni*16 + lm)*32 + quad*8];
#pragma unroll
    for (int mi = 0; mi < 2; mi++) {
      bf16x8 pf = *(const bf16x8*)&Ps[wave][(mi*16 + lm)*32 + quad*8];
#pragma unroll
      for (int ni = 0; ni < 4; ni++)
        o[mi][ni] = __builtin_amdgcn_mfma_f32_16x16x32_bf16(pf, vf[ni], o[mi][ni], 0, 0, 0);
    }
  }

  // epilogue: O / l, store bf16 [B,H,S,hd] (== values.reshape flat layout)
#pragma unroll
  for (int mi = 0; mi < 2; mi++)
#pragma unroll
    for (int r = 0; r < 4; r++) {
      float inv = 1.0f / lst[mi][r];
      int grow = rowbase + mi*16 + quad*4 + r;
#pragma unroll
      for (int ni = 0; ni < 4; ni++)
        Ob[((size_t)bh*SEQ + grow)*HDIM + ni*16 + lm] = f2bf(o[mi][ni][r] * inv);
    }
}

extern "C" void kernel_launch(void* const* d_in, const int* in_sizes, int n_in,
                              void* d_out, int out_size, void* d_ws, size_t ws_size,
                              hipStream_t stream) {
  const float* x    = (const float*)d_in[0];
  const float* Wqkv = (const float*)d_in[1];
  const float* bqkv = (const float*)d_in[2];
  const float* Wo   = (const float*)d_in[3];
  const float* bo   = (const float*)d_in[4];
  float* out = (float*)d_out;

  char* ws = (char*)d_ws;
  unsigned short* Xbf    = (unsigned short*)(ws);              //  8 MiB
  unsigned short* Wqkvbf = (unsigned short*)(ws + 8388608);    //  6 MiB
  unsigned short* Wobf   = (unsigned short*)(ws + 14680064);   //  2 MiB
  unsigned short* Qb     = (unsigned short*)(ws + 16777216);   //  8 MiB [B,H,S,hd]
  unsigned short* Kb     = (unsigned short*)(ws + 25165824);   //  8 MiB [B,H,S,hd]
  unsigned short* VTb    = (unsigned short*)(ws + 33554432);   //  8 MiB [B,H,hd,S]
  unsigned short* Ob     = (unsigned short*)(ws + 41943040);   //  8 MiB [B,H,S,hd]

  cvt_bf16_kernel<<<4096, 256, 0, stream>>>((const float4*)x,    (ushort4*)Xbf,    1048576);
  cvt_bf16_kernel<<<3072, 256, 0, stream>>>((const float4*)Wqkv, (ushort4*)Wqkvbf,  786432);
  cvt_bf16_kernel<<<1024, 256, 0, stream>>>((const float4*)Wo,   (ushort4*)Wobf,    262144);

  gemm_bt_kernel<0><<<dim3(24, 32), 256, 0, stream>>>(
      Xbf, Wqkvbf, bqkv, nullptr, Qb, Kb, VTb, MROWS, NQKV, D_MODEL);

  flash_attn_kernel<<<dim3(16, 32), 256, 0, stream>>>(Qb, Kb, VTb, Ob);

  gemm_bt_kernel<1><<<dim3(8, 32), 256, 0, stream>>>(
      Ob, Wobf, bo, out, nullptr, nullptr, nullptr, MROWS, D_MODEL, D_MODEL);
}

// Round 2
// 257.805 us; speedup vs baseline: 1.2867x; 1.2867x over previous
//
#include <hip/hip_runtime.h>

typedef __attribute__((ext_vector_type(8))) short bf16x8;
typedef __attribute__((ext_vector_type(4))) float f32x4;

#define D_MODEL 1024
#define NHEADS 16
#define HDIM 64
#define SEQ 2048
#define BATCH 2
#define MROWS (BATCH*SEQ)   // 4096
#define NQKV (3*D_MODEL)    // 3072
// softmax in exp2 domain: fold 1/sqrt(64) * log2(e) into Q scale
#define QSCALE 0.1803368801111204f

__device__ __forceinline__ unsigned short f2bf(float f) {
  unsigned int u = __float_as_uint(f);
  u += 0x7FFF + ((u >> 16) & 1);   // RNE
  return (unsigned short)(u >> 16);
}

__device__ __forceinline__ unsigned int pack2bf(float a, float b) {
#if __has_builtin(__builtin_amdgcn_cvt_pk_bf16_f32)
  auto r = __builtin_amdgcn_cvt_pk_bf16_f32(a, b);
  unsigned int u; __builtin_memcpy(&u, &r, 4);
  return u;
#else
  return ((unsigned int)f2bf(b) << 16) | (unsigned int)f2bf(a);
#endif
}

// async global->LDS, 16B per lane. LDS dest must be wave-uniform base + lane*16.
__device__ __forceinline__ void gload16(const void* g, void* l) {
  __builtin_amdgcn_global_load_lds((const __attribute__((address_space(1))) void*)g,
                                   (__attribute__((address_space(3))) void*)l, 16, 0, 0);
}

__global__ void cvt_bf16_kernel(const float4* __restrict__ src,
                                ushort4* __restrict__ dst, int n4) {
  int i = blockIdx.x * blockDim.x + threadIdx.x;
  if (i < n4) {
    float4 v = src[i];
    ushort4 o;
    o.x = f2bf(v.x); o.y = f2bf(v.y); o.z = f2bf(v.z); o.w = f2bf(v.w);
    dst[i] = o;
  }
}

// C[M,N] = A[M,K](bf16) @ B[N,K]^T(bf16) + bias
// MODE 0: scatter epilogue into Q/K/V^T bf16 (QKV projection; Q pre-scaled)
// MODE 1: plain fp32 store (output projection)
template<int MODE>
__global__ __launch_bounds__(256) void gemm_bt_kernel(
    const unsigned short* __restrict__ A,
    const unsigned short* __restrict__ Bm,
    const float* __restrict__ bias,
    float* __restrict__ outF,
    unsigned short* __restrict__ Qb,
    unsigned short* __restrict__ Kb,
    unsigned short* __restrict__ VTb,
    int M, int N, int K)
{
  __shared__ __align__(16) unsigned short As[128*32];
  __shared__ __align__(16) unsigned short Bs[128*32];
  const int tid = threadIdx.x;
  const int wave = tid >> 6, lane = tid & 63;
  const int lm = lane & 15, quad = lane >> 4;
  const int wm = (wave >> 1) * 64, wn = (wave & 1) * 64;
  const int m0 = blockIdx.y * 128, n0 = blockIdx.x * 128;

  f32x4 acc[4][4] = {};

  for (int k0 = 0; k0 < K; k0 += 32) {
    __syncthreads();
#pragma unroll
    for (int i = 0; i < 2; i++) {
      int linear = (i * 256 + tid) * 8;          // shorts; lane-contiguous 16B in LDS
      int row = linear >> 5, col = linear & 31;
      gload16(&A[(size_t)(m0 + row) * K + k0 + col], &As[linear]);
      gload16(&Bm[(size_t)(n0 + row) * K + k0 + col], &Bs[linear]);
    }
    __syncthreads();
    bf16x8 af[4], bfr[4];
#pragma unroll
    for (int mi = 0; mi < 4; mi++)
      af[mi] = *(const bf16x8*)&As[(wm + mi*16 + lm)*32 + quad*8];
#pragma unroll
    for (int ni = 0; ni < 4; ni++)
      bfr[ni] = *(const bf16x8*)&Bs[(wn + ni*16 + lm)*32 + quad*8];
#pragma unroll
    for (int mi = 0; mi < 4; mi++)
#pragma unroll
      for (int ni = 0; ni < 4; ni++)
        acc[mi][ni] = __builtin_amdgcn_mfma_f32_16x16x32_bf16(af[mi], bfr[ni], acc[mi][ni], 0, 0, 0);
  }

#pragma unroll
  for (int mi = 0; mi < 4; mi++)
#pragma unroll
    for (int ni = 0; ni < 4; ni++)
#pragma unroll
      for (int r = 0; r < 4; r++) {
        int row = m0 + wm + mi*16 + quad*4 + r;   // C/D: row=(lane>>4)*4+reg
        int col = n0 + wn + ni*16 + lm;           //      col=lane&15
        float v = acc[mi][ni][r] + bias[col];
        if (MODE == 1) {
          outF[(size_t)row * N + col] = v;
        } else {
          int b = row >> 11, s = row & (SEQ - 1);
          int h = col / 192;
          int rr = col - h * 192;
          int t = rr >> 6, e = rr & 63;
          int bh = b * NHEADS + h;
          if (t == 0)      Qb[((size_t)bh*SEQ + s)*HDIM + e] = f2bf(v * QSCALE);
          else if (t == 1) Kb[((size_t)bh*SEQ + s)*HDIM + e] = f2bf(v);
          else             VTb[((size_t)bh*HDIM + e)*SEQ + s] = f2bf(v);
        }
      }
}

// Causal flash attention, S^T orientation.
// Grid (S/64, B*H); block = 4 waves; wave w owns 16 Q-rows (one query per lane
// column lm). 64-key LDS stages. S^T = K@Q^T puts softmax reduction mostly
// in-lane (2 shuffles); P^T -> PV via packed-b32 LDS transpose; O^T = V^T@P^T.
#define LPAD 72   // LDS row stride in shorts (144B: 16B-aligned, conflict-breaking)
__global__ __launch_bounds__(256) void flash_attn_kernel(
    const unsigned short* __restrict__ Qb,
    const unsigned short* __restrict__ Kb,
    const unsigned short* __restrict__ VTb,
    unsigned short* __restrict__ Ob)
{
  const int qt = (gridDim.x - 1) - blockIdx.x;   // heavy tiles first
  const int bh = blockIdx.y;
  const int tid = threadIdx.x;
  const int wave = tid >> 6, lane = tid & 63;
  const int lm = lane & 15, quad = lane >> 4;
  const int q0 = qt * 64;
  const int rowq = q0 + wave * 16;
  const int query = rowq + lm;                   // this lane's query row

  __shared__ __align__(16) unsigned short Ks[64*LPAD];     // [key][e]
  __shared__ __align__(16) unsigned short Vs[64*LPAD];     // [e][key] (V^T)
  __shared__ __align__(16) unsigned short Ps[4*16*LPAD];   // per-wave P [query][key]

  // Q fragment (B-operand [n=query=lm][k=e=quad*8+j]), Q pre-scaled
  bf16x8 qf[2];
#pragma unroll
  for (int kc = 0; kc < 2; kc++)
    qf[kc] = *(const bf16x8*)&Qb[((size_t)bh*SEQ + query)*HDIM + kc*32 + quad*8];

  f32x4 o[4] = {};          // O^T tiles: (e = ei*16+quad*4+r, q = lm)
  float m_run = -1e30f, l_run = 0.f;

  unsigned short* Pw = &Ps[(wave*16 + lm) * LPAD];

  for (int kt = 0; kt <= qt; ++kt) {
    const int k0 = kt * 64;
    __syncthreads();
#pragma unroll
    for (int i = 0; i < 2; i++) {
      int lin = i * 2048 + tid * 8;
      int r = lin >> 6, c = lin & 63;
      *(uint4*)&Ks[r*LPAD + c] = *(const uint4*)&Kb[((size_t)bh*SEQ + k0 + r)*HDIM + c];
      *(uint4*)&Vs[r*LPAD + c] = *(const uint4*)&VTb[((size_t)bh*HDIM + r)*SEQ + k0 + c];
    }
    __syncthreads();

    // S^T = K @ Q^T : C tiles (row = key-in-tile, col = query)
    f32x4 sc[4] = {};
#pragma unroll
    for (int kc = 0; kc < 2; kc++)
#pragma unroll
      for (int mi = 0; mi < 4; mi++) {
        bf16x8 kf = *(const bf16x8*)&Ks[(mi*16 + lm)*LPAD + kc*32 + quad*8];
        sc[mi] = __builtin_amdgcn_mfma_f32_16x16x32_bf16(kf, qf[kc], sc[mi], 0, 0, 0);
      }

    if (k0 + 63 > rowq) {    // causal mask needed in this stage (wave-uniform)
#pragma unroll
      for (int mi = 0; mi < 4; mi++)
#pragma unroll
        for (int r = 0; r < 4; r++) {
          int key = k0 + mi*16 + quad*4 + r;
          if (key > query) sc[mi][r] = -1e30f;
        }
    }

    // online softmax: all 16 in-lane values belong to query `lm`
    float mx = sc[0][0];
#pragma unroll
    for (int mi = 0; mi < 4; mi++)
#pragma unroll
      for (int r = 0; r < 4; r++) mx = fmaxf(mx, sc[mi][r]);
    mx = fmaxf(mx, __shfl_xor(mx, 16, 64));
    mx = fmaxf(mx, __shfl_xor(mx, 32, 64));
    float mnew = fmaxf(m_run, mx);
    float alpha = exp2f(m_run - mnew);
    float p[4][4];
    float rs = 0.f;
#pragma unroll
    for (int mi = 0; mi < 4; mi++)
#pragma unroll
      for (int r = 0; r < 4; r++) {
        p[mi][r] = exp2f(sc[mi][r] - mnew);
        rs += p[mi][r];
      }
    rs += __shfl_xor(rs, 16, 64);
    rs += __shfl_xor(rs, 32, 64);
    l_run = l_run * alpha + rs;
    m_run = mnew;
#pragma unroll
    for (int ei = 0; ei < 4; ei++)
#pragma unroll
      for (int r = 0; r < 4; r++) o[ei][r] *= alpha;

    // P^T -> LDS as P[query][key] (packed bf16 pairs along r)
#pragma unroll
    for (int mi = 0; mi < 4; mi++) {
      *(unsigned int*)&Pw[mi*16 + quad*4]     = pack2bf(p[mi][0], p[mi][1]);
      *(unsigned int*)&Pw[mi*16 + quad*4 + 2] = pack2bf(p[mi][2], p[mi][3]);
    }
    asm volatile("s_waitcnt lgkmcnt(0)" ::: "memory");  // same-wave write->read

    // O^T += V^T @ P^T : A = V^T[e][key], B = P[q][key]
#pragma unroll
    for (int kc = 0; kc < 2; kc++) {
      bf16x8 pf = *(const bf16x8*)&Pw[kc*32 + quad*8];
#pragma unroll
      for (int ei = 0; ei < 4; ei++) {
        bf16x8 vf = *(const bf16x8*)&Vs[(ei*16 + lm)*LPAD + kc*32 + quad*8];
        o[ei] = __builtin_amdgcn_mfma_f32_16x16x32_bf16(vf, pf, o[ei], 0, 0, 0);
      }
    }
  }

  // epilogue: O^T/l -> Ob[bh][s][e] (bf16), 8B packed stores
  float inv = 1.0f / l_run;
  size_t obase = ((size_t)bh*SEQ + query) * HDIM;
#pragma unroll
  for (int ei = 0; ei < 4; ei++) {
    uint2 u;
    u.x = pack2bf(o[ei][0]*inv, o[ei][1]*inv);
    u.y = pack2bf(o[ei][2]*inv, o[ei][3]*inv);
    *(uint2*)&Ob[obase + ei*16 + quad*4] = u;
  }
}

extern "C" void kernel_launch(void* const* d_in, const int* in_sizes, int n_in,
                              void* d_out, int out_size, void* d_ws, size_t ws_size,
                              hipStream_t stream) {
  const float* x    = (const float*)d_in[0];
  const float* Wqkv = (const float*)d_in[1];
  const float* bqkv = (const float*)d_in[2];
  const float* Wo   = (const float*)d_in[3];
  const float* bo   = (const float*)d_in[4];
  float* out = (float*)d_out;

  char* ws = (char*)d_ws;
  unsigned short* Xbf    = (unsigned short*)(ws);              //  8 MiB
  unsigned short* Wqkvbf = (unsigned short*)(ws + 8388608);    //  6 MiB
  unsigned short* Wobf   = (unsigned short*)(ws + 14680064);   //  2 MiB
  unsigned short* Qb     = (unsigned short*)(ws + 16777216);   //  8 MiB [B,H,S,hd]
  unsigned short* Kb     = (unsigned short*)(ws + 25165824);   //  8 MiB [B,H,S,hd]
  unsigned short* VTb    = (unsigned short*)(ws + 33554432);   //  8 MiB [B,H,hd,S]
  unsigned short* Ob     = (unsigned short*)(ws + 41943040);   //  8 MiB [B,H,S,hd]

  cvt_bf16_kernel<<<4096, 256, 0, stream>>>((const float4*)x,    (ushort4*)Xbf,    1048576);
  cvt_bf16_kernel<<<3072, 256, 0, stream>>>((const float4*)Wqkv, (ushort4*)Wqkvbf,  786432);
  cvt_bf16_kernel<<<1024, 256, 0, stream>>>((const float4*)Wo,   (ushort4*)Wobf,    262144);

  gemm_bt_kernel<0><<<dim3(24, 32), 256, 0, stream>>>(
      Xbf, Wqkvbf, bqkv, nullptr, Qb, Kb, VTb, MROWS, NQKV, D_MODEL);

  flash_attn_kernel<<<dim3(32, 32), 256, 0, stream>>>(Qb, Kb, VTb, Ob);

  gemm_bt_kernel<1><<<dim3(8, 32), 256, 0, stream>>>(
      Ob, Wobf, bo, out, nullptr, nullptr, nullptr, MROWS, D_MODEL, D_MODEL);
}